// Round 10
// baseline (34.022 us; speedup 1.0000x reference)
//
#include <hip/hip_runtime.h>
#include <hip/hip_bf16.h>

typedef short short8 __attribute__((ext_vector_type(8)));
typedef float f32x4 __attribute__((ext_vector_type(4)));

__device__ inline unsigned short f2bf(float f) {
    unsigned u = __builtin_bit_cast(unsigned, f);
    u += 0x7FFFu + ((u >> 16) & 1u);          // round-to-nearest-even
    return (unsigned short)(u >> 16);
}

// ---------------------------------------------------------------------------
// prep: Wm[d][c] = 0.25 * sum_h Wv[h*64+d][c], packed in MFMA B-fragment order:
//   Bf[((ct*8+kc)*64 + lane)*8 + j] = bf16(Wm[ct*16 + lane%16][kc*32 + (lane/16)*8 + j])
// bm[d] = 0.25 * sum_h bv[h*64+d]
// ---------------------------------------------------------------------------
__global__ __launch_bounds__(256)
void k_prep(const float* __restrict__ Wv, const float* __restrict__ bv,
            unsigned short* __restrict__ Bf, float* __restrict__ bm)
{
    const int t = blockIdx.x * 256 + threadIdx.x;   // 0..16383
    const int fi = t >> 9;                          // fragment index 0..31
    const int lane = (t >> 3) & 63;
    const int j = t & 7;
    const int ct = fi >> 3, kc = fi & 7;
    const int d = ct * 16 + (lane & 15);
    const int c = kc * 32 + (lane >> 4) * 8 + j;
    const float s = 0.25f * (Wv[(size_t)d * 256 + c] +
                             Wv[(size_t)(64 + d) * 256 + c] +
                             Wv[(size_t)(128 + d) * 256 + c] +
                             Wv[(size_t)(192 + d) * 256 + c]);
    Bf[t] = f2bf(s);
    if (t < 64)
        bm[t] = 0.25f * (bv[t] + bv[64 + t] + bv[128 + t] + bv[192 + t]);
}

// ---------------------------------------------------------------------------
// main: out[n][d] = sum_c source[n][c] * Wm[d][c] + bm[d]
// 256 threads = 4 waves; block owns 64 rows, wave owns 16.
// REGISTER-LEAN: __launch_bounds__(256,8) forces <=64 VGPR -> 8 waves/SIMD
// (copy-kernel occupancy regime; wave-level MLP is what saturates HBM).
// K-loop is a 2-deep pipeline: hold only current+next 32 B of A per lane.
// B fragments from global/L2. Epilogue: LDS bounce -> contiguous 1 KB stores
// (R9, proven).
// ---------------------------------------------------------------------------
__global__ __launch_bounds__(256, 8)
void k_vmean(const float* __restrict__ X, const unsigned short* __restrict__ Bf,
             const float* __restrict__ bm, float* __restrict__ out, int N)
{
    __shared__ float Xt[4][16 * 68];                // 17 KB (wave-private tiles)

    const int t = threadIdx.x;
    const int wave = t >> 6, lane = t & 63;
    const int col_lo = lane & 15, kgrp = lane >> 4;
    const int rowbase = blockIdx.x * 64 + wave * 16;

    const int arow0 = rowbase + (lane & 15);
    const int arow = arow0 < N ? arow0 : N - 1;     // clamp tail rows
    const float* xrow = X + (size_t)arow * 256 + kgrp * 8;

    float bias[4];
#pragma unroll
    for (int ct = 0; ct < 4; ++ct) bias[ct] = bm[ct * 16 + col_lo];

    // 2-deep software pipeline over the 8 K-chunks
    f32x4 c0 = *(const f32x4*)(xrow);
    f32x4 c1 = *(const f32x4*)(xrow + 4);
    f32x4 acc[4] = {};
#pragma unroll
    for (int kc = 0; kc < 8; ++kc) {
        f32x4 n0, n1;
        if (kc < 7) {
            n0 = *(const f32x4*)(xrow + (kc + 1) * 32);
            n1 = *(const f32x4*)(xrow + (kc + 1) * 32 + 4);
        }
        short8 a;
        a[0] = (short)f2bf(c0[0]); a[1] = (short)f2bf(c0[1]);
        a[2] = (short)f2bf(c0[2]); a[3] = (short)f2bf(c0[3]);
        a[4] = (short)f2bf(c1[0]); a[5] = (short)f2bf(c1[1]);
        a[6] = (short)f2bf(c1[2]); a[7] = (short)f2bf(c1[3]);
#pragma unroll
        for (int ct = 0; ct < 4; ++ct) {
            const short8 b = *(const short8*)&Bf[((ct * 8 + kc) * 64 + lane) * 8];
            acc[ct] = __builtin_amdgcn_mfma_f32_16x16x32_bf16(a, b, acc[ct], 0, 0, 0);
        }
        if (kc < 7) { c0 = n0; c1 = n1; }
    }

    // epilogue A: acc -> LDS (C/D layout: col=lane&15, row=(lane>>4)*4+reg)
    float* wtile = &Xt[wave][0];
#pragma unroll
    for (int ct = 0; ct < 4; ++ct) {
#pragma unroll
        for (int r = 0; r < 4; ++r)
            wtile[(kgrp * 4 + r) * 68 + ct * 16 + col_lo] = acc[ct][r] + bias[ct];
    }
    // same-wave LDS dependency only (no barrier)

    // epilogue B: instr s = rows [s*4, s*4+4) x all 64 cols = contiguous 1 KB
#pragma unroll
    for (int s = 0; s < 4; ++s) {
        const int rho = s * 4 + (lane >> 4);
        const int c4 = lane & 15;
        const f32x4 v = *(const f32x4*)&wtile[rho * 68 + c4 * 4];
        const int grow = rowbase + rho;
        if (grow < N)
            *(f32x4*)&out[(size_t)grow * 64 + c4 * 4] = v;
    }
}

extern "C" void kernel_launch(void* const* d_in, const int* in_sizes, int n_in,
                              void* d_out, int out_size, void* d_ws, size_t ws_size,
                              hipStream_t stream)
{
    const float* sx = (const float*)d_in[1];        // source_input
    const float* Wv = (const float*)d_in[6];
    const float* bv = (const float*)d_in[7];
    float* out = (float*)d_out;

    unsigned short* Bf = (unsigned short*)d_ws;                 // 32 KB
    float* bm = (float*)((char*)d_ws + 16384 * sizeof(unsigned short));

    const int N = in_sizes[0] / 256;
    const int nblk = (N + 63) / 64;

    k_prep<<<64, 256, 0, stream>>>(Wv, bv, Bf, bm);
    k_vmean<<<nblk, 256, 0, stream>>>(sx, Bf, bm, out, N);
}